// Round 3
// baseline (401.608 us; speedup 1.0000x reference)
//
#include <hip/hip_runtime.h>
#include <math.h>

#define BATCH 512
#define NPTS  512

// w(d) = exp(-acos(clamp(d,-1,1))) = exp2(-acos(d)*log2e)
// acos(|d|)*log2e = sqrt(1-|d|) * P(|d|); P = A&S 4.4.46 deg-7 poly
// pre-multiplied by log2(e) (|acos err| ~ 2e-8 rad).
__device__ __forceinline__ float pair_w(float d) {
    d = __builtin_amdgcn_fmed3f(d, -1.f, 1.f);     // 1 op clamp
    float a  = fabsf(d);                           // source modifier
    float t  = 1.f - a;
    float sq = __builtin_amdgcn_sqrtf(t);
    float p  = fmaf(-0.00182139f, a, 0.00962291f);
    p = fmaf(p, a, -0.02465296f);
    p = fmaf(p, a,  0.04456757f);
    p = fmaf(p, a, -0.07238623f);
    p = fmaf(p, a,  0.12836958f);
    p = fmaf(p, a, -0.30960063f);
    p = fmaf(p, a,  2.26618007f);                  // pi/2 * log2e
    float q = sq * p;                              // acos(|d|)*log2e
    float e = (d < 0.f) ? (4.53236014f - q) : q;   // pi*log2e - q for d<0
    return __builtin_amdgcn_exp2f(-e);             // neg folds into modifier
}

__global__ __launch_bounds__(NPTS) void normals_fused_kernel(
    const float* __restrict__ normals, float* __restrict__ out)
{
    // Mirrored arrays: index tid+k (k<=256) never wraps -> offset immediates.
    __shared__ float4 sn2 [2 * NPTS];   // packed xyz_ , duplicated
    __shared__ float  acc2[2 * NPTS];   // transpose-row accumulators (atomic)
    const int b   = blockIdx.x;
    const int tid = threadIdx.x;
    const float* base = normals + (size_t)b * NPTS * 3;

    float* snf = (float*)sn2;
    for (int k = tid; k < NPTS * 3; k += NPTS) {
        float v = base[k];
        int row = k / 3, c = k - row * 3;
        snf[row * 4 + c]          = v;
        snf[(row + NPTS) * 4 + c] = v;
    }
    acc2[tid]        = 0.f;
    acc2[tid + NPTS] = 0.f;
    __syncthreads();

    const float4 ni = sn2[tid];
    const float  xi = ni.x, yi = ni.y, zi = ni.z;

    // Symmetric scheme: pair {i, i+k mod 512} computed ONCE (k=1..255),
    // contributing to row i (register s) and row i+k (LDS atomic).
    float s = 0.f;
    #pragma unroll 5
    for (int k = 1; k < NPTS / 2; ++k) {          // 255 iters, 5 | 255
        float4 nj = sn2[tid + k];
        float d = fmaf(xi, nj.x, fmaf(yi, nj.y, zi * nj.z));
        float w = pair_w(d);
        s += w;
        atomicAdd(&acc2[tid + k], w);             // ds_add_f32, bijective addrs
    }
    {   // k = 256: mirror pair is the partner thread's own k=256 step.
        float4 nj = sn2[tid + NPTS / 2];
        float d = fmaf(xi, nj.x, fmaf(yi, nj.y, zi * nj.z));
        s += pair_w(d);
    }
    __syncthreads();
    s += acc2[tid] + acc2[tid + NPTS];            // gather transpose halves

    // Global-max division skipped: uniform positive scale cancels under the
    // final normalization (verified R0/R1: absmax 0.0).
    float ax = s * xi, ay = s * yi, az = s * zi;

    for (int off = 32; off > 0; off >>= 1) {
        ax += __shfl_down(ax, off, 64);
        ay += __shfl_down(ay, off, 64);
        az += __shfl_down(az, off, 64);
    }

    __shared__ float rx[8], ry[8], rz[8];
    const int wave = tid >> 6, lane = tid & 63;
    if (lane == 0) { rx[wave] = ax; ry[wave] = ay; rz[wave] = az; }
    __syncthreads();

    if (tid == 0) {
        float nx = 0.f, ny = 0.f, nz = 0.f;
        #pragma unroll
        for (int w = 0; w < 8; ++w) { nx += rx[w]; ny += ry[w]; nz += rz[w]; }
        float len2 = fmaf(nx, nx, fmaf(ny, ny, nz * nz));
        float inv  = rsqrtf(fmaxf(len2, 1e-20f));
        out[b * 3 + 0] = nx * inv;
        out[b * 3 + 1] = ny * inv;
        out[b * 3 + 2] = nz * inv;
    }
}

extern "C" void kernel_launch(void* const* d_in, const int* in_sizes, int n_in,
                              void* d_out, int out_size, void* d_ws, size_t ws_size,
                              hipStream_t stream) {
    const float* normals = (const float*)d_in[0];
    // d_in[1] (weights) is mathematically unused by the reference.
    float* out = (float*)d_out;
    normals_fused_kernel<<<BATCH, NPTS, 0, stream>>>(normals, out);
}

// Round 4
// 103.251 us; speedup vs baseline: 3.8896x; 3.8896x over previous
//
#include <hip/hip_runtime.h>
#include <math.h>

#define BATCH 512
#define NPTS  512

// w(d) = exp(-acos(clamp(d,-1,1))) = exp2(-acos(d)*log2e)  — verbatim from R2
// (verified absmax 0.0). A&S 4.4.46 deg-7 poly pre-scaled by log2(e).
__device__ __forceinline__ float pair_w(float d) {
    d = __builtin_amdgcn_fmed3f(d, -1.f, 1.f);
    float a  = fabsf(d);
    float t  = 1.f - a;
    float sq = __builtin_amdgcn_sqrtf(t);
    float p  = fmaf(-0.00182139f, a, 0.00962291f);
    p = fmaf(p, a, -0.02465296f);
    p = fmaf(p, a,  0.04456757f);
    p = fmaf(p, a, -0.07238623f);
    p = fmaf(p, a,  0.12836958f);
    p = fmaf(p, a, -0.30960063f);
    p = fmaf(p, a,  2.26618007f);
    float q = sq * p;
    float e = (d < 0.f) ? (4.53236014f - q) : q;
    return __builtin_amdgcn_exp2f(-e);
}

// One chunk-pair segment: lane l pairs its own point A_l against traveling
// points B_{(l+k)&63} read from the MIRRORED SoA copy (4B stride, conflict-
// free, unrolled immediate offsets). B-row contribution pulled in-register
// via ds_bpermute from lane (l-k): that lane computed pair (A_{l-k}, B_l).
template<int K0, int K1>
__device__ __forceinline__ void do_seg(
    const float* __restrict__ sx, const float* __restrict__ sy,
    const float* __restrict__ sz, int v, int lane,
    float xi, float yi, float zi, float& accA, float* racc)
{
    const int bidx = v * 128 + lane;
    float accB = 0.f;
    #pragma unroll 16
    for (int k = K0; k <= K1; ++k) {
        float xj = sx[bidx + k];
        float yj = sy[bidx + k];
        float zj = sz[bidx + k];
        float d  = fmaf(xi, xj, fmaf(yi, yj, zi * zj));
        float w  = pair_w(d);
        accA += w;
        int src = ((lane - k) & 63) << 2;
        accB += __int_as_float(
            __builtin_amdgcn_ds_bpermute(src, __float_as_int(w)));
    }
    atomicAdd(&racc[v * 64 + lane], accB);   // one atomic per SEGMENT
}

__global__ __launch_bounds__(NPTS) void normals_fused_kernel(
    const float* __restrict__ normals, float* __restrict__ out)
{
    __shared__ float sx[1024], sy[1024], sz[1024];  // mirrored SoA: chunk c at
    __shared__ float racc[NPTS];                    // [128c..128c+127], dup'd
    __shared__ float rx[8], ry[8], rz[8];
    const int b    = blockIdx.x;
    const int tid  = threadIdx.x;
    const int wave = tid >> 6, lane = tid & 63;
    const float* base = normals + (size_t)b * NPTS * 3;

    for (int k = tid; k < NPTS * 3; k += NPTS) {
        float val = base[k];
        int r = k / 3, c = k - r * 3;
        int idx = (r >> 6) * 128 + (r & 63);
        float* dst = (c == 0) ? sx : (c == 1) ? sy : sz;
        dst[idx]      = val;
        dst[idx + 64] = val;
    }
    racc[tid] = 0.f;
    __syncthreads();

    const int own = wave * 128 + lane;
    const float xi = sx[own], yi = sy[own], zi = sz[own];
    float accA = 0.f;

    // self-chunk: k=1..31 both-sided; k=32 own-row only (partner's own k=32
    // step covers the mirror) — diagonal never computed.
    do_seg<1, 31>(sx, sy, sz, wave, lane, xi, yi, zi, accA, racc);
    {
        float d = fmaf(xi, sx[own + 32], fmaf(yi, sy[own + 32], zi * sz[own + 32]));
        accA += pair_w(d);
    }
    // three full cross chunk-pairs
    do_seg<0, 63>(sx, sy, sz, (wave + 1) & 7, lane, xi, yi, zi, accA, racc);
    do_seg<0, 63>(sx, sy, sz, (wave + 2) & 7, lane, xi, yi, zi, accA, racc);
    do_seg<0, 63>(sx, sy, sz, (wave + 3) & 7, lane, xi, yi, zi, accA, racc);
    // split pair {w, w+4}: low wave covers (j-i)%64 in [0,31], high in [32,63]
    if (wave < 4) do_seg<0, 31>(sx, sy, sz, wave + 4, lane, xi, yi, zi, accA, racc);
    else          do_seg<1, 32>(sx, sy, sz, wave - 4, lane, xi, yi, zi, accA, racc);

    __syncthreads();
    float s = accA + racc[tid];

    // Global-max division skipped: uniform positive scale cancels under the
    // final normalization (verified R0-R2: absmax 0.0).
    float ax = s * xi, ay = s * yi, az = s * zi;

    for (int off = 32; off > 0; off >>= 1) {
        ax += __shfl_down(ax, off, 64);
        ay += __shfl_down(ay, off, 64);
        az += __shfl_down(az, off, 64);
    }
    if (lane == 0) { rx[wave] = ax; ry[wave] = ay; rz[wave] = az; }
    __syncthreads();

    if (tid == 0) {
        float nx = 0.f, ny = 0.f, nz = 0.f;
        #pragma unroll
        for (int w = 0; w < 8; ++w) { nx += rx[w]; ny += ry[w]; nz += rz[w]; }
        float len2 = fmaf(nx, nx, fmaf(ny, ny, nz * nz));
        float inv  = rsqrtf(fmaxf(len2, 1e-20f));
        out[b * 3 + 0] = nx * inv;
        out[b * 3 + 1] = ny * inv;
        out[b * 3 + 2] = nz * inv;
    }
}

extern "C" void kernel_launch(void* const* d_in, const int* in_sizes, int n_in,
                              void* d_out, int out_size, void* d_ws, size_t ws_size,
                              hipStream_t stream) {
    const float* normals = (const float*)d_in[0];
    // d_in[1] (weights) is mathematically unused by the reference.
    float* out = (float*)d_out;
    normals_fused_kernel<<<BATCH, NPTS, 0, stream>>>(normals, out);
}

// Round 6
// 101.964 us; speedup vs baseline: 3.9387x; 1.0126x over previous
//
#include <hip/hip_runtime.h>
#include <math.h>

#define BATCH 512
#define NPTS  512

// Rotate a float ACROSS the full wave64 so that dst[l] = src[(l+1) & 63].
// DPP ctrl 0x134 = wave_rol:1. (R5 post-mortem: 0x13C wave_ror:1 is the
// OPPOSITE direction — dst[l] = src[(l-1)&63] — which scrambled the
// traveling-accumulator writeback and the {w,w+4} split coverage.)
__device__ __forceinline__ float rot1(float v) {
    return __int_as_float(__builtin_amdgcn_update_dpp(
        __float_as_int(v), __float_as_int(v), 0x134, 0xF, 0xF, false));
}

// w(d) = exp(-acos(clamp(d,-1,1))) = exp2(-acos(d)*log2e)  — verbatim since R2
// (verified absmax 0.0). A&S 4.4.46 deg-7 poly pre-scaled by log2(e).
__device__ __forceinline__ float pair_w(float d) {
    d = __builtin_amdgcn_fmed3f(d, -1.f, 1.f);
    float a  = fabsf(d);
    float t  = 1.f - a;
    float sq = __builtin_amdgcn_sqrtf(t);
    float p  = fmaf(-0.00182139f, a, 0.00962291f);
    p = fmaf(p, a, -0.02465296f);
    p = fmaf(p, a,  0.04456757f);
    p = fmaf(p, a, -0.07238623f);
    p = fmaf(p, a,  0.12836958f);
    p = fmaf(p, a, -0.30960063f);
    p = fmaf(p, a,  2.26618007f);
    float q = sq * p;
    float e = (d < 0.f) ? (4.53236014f - q) : q;
    return __builtin_amdgcn_exp2f(-e);
}

// Segment against B-chunk v, steps k=K0..K1 (pair: lane l vs B_{(l+k)&63}).
// B chunk lives in registers, rotated 1 lane/step; the transpose-row partial
// sum `bacc` travels WITH the B point (rotates in lockstep), so the inner
// loop touches no LDS at all. One ds-atomic writeback per segment.
// TAIL: one extra step at alignment K1+1 adding to accA only (self-chunk
// k=32 half-pair; the mirror is the partner's own tail).
template<int K0, int K1, bool TAIL>
__device__ __forceinline__ void do_seg(
    const float* __restrict__ sx, const float* __restrict__ sy,
    const float* __restrict__ sz, int v, int lane,
    float xi, float yi, float zi, float& accA, float* __restrict__ racc)
{
    const int bi = v * 64 + lane;
    float bx = sx[bi], by = sy[bi], bz = sz[bi];
    float bacc = 0.f;
    #pragma unroll
    for (int r = 0; r < K0; ++r) { bx = rot1(bx); by = rot1(by); bz = rot1(bz); }
    #pragma unroll 8
    for (int k = K0; k <= K1; ++k) {
        float d = fmaf(xi, bx, fmaf(yi, by, zi * bz));
        float w = pair_w(d);
        accA += w;            // row i
        bacc += w;            // row (i+k) — traveling register
        bx = rot1(bx); by = rot1(by); bz = rot1(bz); bacc = rot1(bacc);
    }
    if (TAIL) {               // alignment K1+1, own-row only
        float d = fmaf(xi, bx, fmaf(yi, by, zi * bz));
        accA += pair_w(d);
    }
    const int m = (lane + K1 + 1) & 63;  // home slot of bacc after rotations
    atomicAdd(&racc[v * 64 + m], bacc);
}

__global__ __launch_bounds__(NPTS) void normals_fused_kernel(
    const float* __restrict__ normals, float* __restrict__ out)
{
    __shared__ float sx[NPTS], sy[NPTS], sz[NPTS];
    __shared__ float racc[NPTS];
    __shared__ float rx[8], ry[8], rz[8];
    const int b    = blockIdx.x;
    const int tid  = threadIdx.x;
    const int wave = tid >> 6, lane = tid & 63;
    const float* base = normals + (size_t)b * NPTS * 3;

    for (int k = tid; k < NPTS * 3; k += NPTS) {
        float val = base[k];
        int r = k / 3, c = k - r * 3;
        float* dst = (c == 0) ? sx : (c == 1) ? sy : sz;
        dst[r] = val;
    }
    racc[tid] = 0.f;
    __syncthreads();

    const float xi = sx[tid], yi = sy[tid], zi = sz[tid];
    float accA = 0.f;

    // Chunk-pair schedule (identical coverage to R3, refcheck'd absmax 0.0):
    // self (k=1..31 both-sided, k=32 own-only tail), 3 full cross pairs,
    // split pair {w, w+4} by k-range. 256 weighted pairs per thread.
    do_seg<1, 31, true >(sx, sy, sz, wave,           lane, xi, yi, zi, accA, racc);
    do_seg<0, 63, false>(sx, sy, sz, (wave + 1) & 7, lane, xi, yi, zi, accA, racc);
    do_seg<0, 63, false>(sx, sy, sz, (wave + 2) & 7, lane, xi, yi, zi, accA, racc);
    do_seg<0, 63, false>(sx, sy, sz, (wave + 3) & 7, lane, xi, yi, zi, accA, racc);
    if (wave < 4) do_seg<0, 31, false>(sx, sy, sz, wave + 4, lane, xi, yi, zi, accA, racc);
    else          do_seg<1, 32, false>(sx, sy, sz, wave - 4, lane, xi, yi, zi, accA, racc);

    __syncthreads();
    float s = accA + racc[tid];

    // Global-max division skipped: uniform positive scale cancels under the
    // final normalization (verified R0-R4: absmax 0.0).
    float ax = s * xi, ay = s * yi, az = s * zi;

    for (int off = 32; off > 0; off >>= 1) {
        ax += __shfl_down(ax, off, 64);
        ay += __shfl_down(ay, off, 64);
        az += __shfl_down(az, off, 64);
    }
    if (lane == 0) { rx[wave] = ax; ry[wave] = ay; rz[wave] = az; }
    __syncthreads();

    if (tid == 0) {
        float nx = 0.f, ny = 0.f, nz = 0.f;
        #pragma unroll
        for (int w = 0; w < 8; ++w) { nx += rx[w]; ny += ry[w]; nz += rz[w]; }
        float len2 = fmaf(nx, nx, fmaf(ny, ny, nz * nz));
        float inv  = rsqrtf(fmaxf(len2, 1e-20f));
        out[b * 3 + 0] = nx * inv;
        out[b * 3 + 1] = ny * inv;
        out[b * 3 + 2] = nz * inv;
    }
}

extern "C" void kernel_launch(void* const* d_in, const int* in_sizes, int n_in,
                              void* d_out, int out_size, void* d_ws, size_t ws_size,
                              hipStream_t stream) {
    const float* normals = (const float*)d_in[0];
    // d_in[1] (weights) is mathematically unused by the reference.
    float* out = (float*)d_out;
    normals_fused_kernel<<<BATCH, NPTS, 0, stream>>>(normals, out);
}

// Round 7
// 87.764 us; speedup vs baseline: 4.5760x; 1.1618x over previous
//
#include <hip/hip_runtime.h>
#include <math.h>

#define BATCH 512
#define NPTS  512

// Rotate a float ACROSS the full wave64 so that dst[l] = src[(l+1) & 63].
// DPP ctrl 0x134 = wave_rol:1 (verified R6, absmax 0.0).
__device__ __forceinline__ float rot1(float v) {
    return __int_as_float(__builtin_amdgcn_update_dpp(
        __float_as_int(v), __float_as_int(v), 0x134, 0xF, 0xF, false));
}

// EXACT path (used only to build the LUT): w(d) = exp2(-acos(d)*log2e),
// A&S 4.4.46 deg-7 poly pre-scaled by log2(e). Verified absmax 0.0 (R2-R6).
// Exact at the endpoints: d=1 -> 1, d=-1 -> e^-pi.
__device__ __forceinline__ float pair_w_exact(float d) {
    d = __builtin_amdgcn_fmed3f(d, -1.f, 1.f);
    float a  = fabsf(d);
    float t  = 1.f - a;
    float sq = __builtin_amdgcn_sqrtf(t);
    float p  = fmaf(-0.00182139f, a, 0.00962291f);
    p = fmaf(p, a, -0.02465296f);
    p = fmaf(p, a,  0.04456757f);
    p = fmaf(p, a, -0.07238623f);
    p = fmaf(p, a,  0.12836958f);
    p = fmaf(p, a, -0.30960063f);
    p = fmaf(p, a,  2.26618007f);
    float q = sq * p;
    float e = (d < 0.f) ? (4.53236014f - q) : q;
    return __builtin_amdgcn_exp2f(-e);
}

// LUT path: 512 cells over [-1,1]; cell i holds {w_i, w_{i+1}-w_i}.
// idx_f = clamp((d+1)*256, 0, 512); linear interp. No transcendentals.
__device__ __forceinline__ float pair_w(float d, const float2* __restrict__ wtab) {
    float idx_f = __builtin_amdgcn_fmed3f(fmaf(d, 256.f, 256.f), 0.f, 512.f);
    int   idx   = (int)idx_f;              // trunc == floor (non-negative)
    idx = min(idx, 511);                   // d==1 -> cell 511, frac 1.0 (exact)
    float frac  = idx_f - (float)idx;
    float2 c = wtab[idx];                  // ds_read_b64
    return fmaf(frac, c.y, c.x);
}

// Segment vs B-chunk v, steps k=K0..K1 (pair: lane l vs B_{(l+k)&63}).
// B chunk + traveling transpose accumulator rotate in registers (R6-verified).
template<int K0, int K1, bool TAIL>
__device__ __forceinline__ void do_seg(
    const float* __restrict__ sx, const float* __restrict__ sy,
    const float* __restrict__ sz, const float2* __restrict__ wtab,
    int v, int lane, float xi, float yi, float zi,
    float& accA, float* __restrict__ racc)
{
    const int bi = v * 64 + lane;
    float bx = sx[bi], by = sy[bi], bz = sz[bi];
    float bacc = 0.f;
    #pragma unroll
    for (int r = 0; r < K0; ++r) { bx = rot1(bx); by = rot1(by); bz = rot1(bz); }
    #pragma unroll 8
    for (int k = K0; k <= K1; ++k) {
        float d = fmaf(xi, bx, fmaf(yi, by, zi * bz));
        float w = pair_w(d, wtab);
        accA += w;            // row i
        bacc += w;            // row (i+k) — traveling register
        bx = rot1(bx); by = rot1(by); bz = rot1(bz); bacc = rot1(bacc);
    }
    if (TAIL) {               // alignment K1+1, own-row only (self-chunk k=32)
        float d = fmaf(xi, bx, fmaf(yi, by, zi * bz));
        accA += pair_w(d, wtab);
    }
    const int m = (lane + K1 + 1) & 63;  // home slot of bacc after rotations
    atomicAdd(&racc[v * 64 + m], bacc);
}

__global__ __launch_bounds__(NPTS) void normals_fused_kernel(
    const float* __restrict__ normals, float* __restrict__ out)
{
    __shared__ float  sx[NPTS], sy[NPTS], sz[NPTS];
    __shared__ float  racc[NPTS];
    __shared__ float2 wtab[512];
    __shared__ float  rx[8], ry[8], rz[8];
    const int b    = blockIdx.x;
    const int tid  = threadIdx.x;
    const int wave = tid >> 6, lane = tid & 63;
    const float* base = normals + (size_t)b * NPTS * 3;

    // Build the w(d) table (one-time; exact poly path).
    {
        float d0 = (float)tid       * (1.f / 256.f) - 1.f;
        float d1 = (float)(tid + 1) * (1.f / 256.f) - 1.f;
        float w0 = pair_w_exact(d0);
        float w1 = pair_w_exact(d1);
        wtab[tid] = make_float2(w0, w1 - w0);
    }
    for (int k = tid; k < NPTS * 3; k += NPTS) {
        float val = base[k];
        int r = k / 3, c = k - r * 3;
        float* dst = (c == 0) ? sx : (c == 1) ? sy : sz;
        dst[r] = val;
    }
    racc[tid] = 0.f;
    __syncthreads();

    const float xi = sx[tid], yi = sy[tid], zi = sz[tid];
    float accA = 0.f;

    // Chunk-pair schedule (R6-verified, absmax 0.0): self (k=1..31 + k=32
    // tail), 3 full cross pairs, split pair {w,w+4}. 256 pairs per thread.
    do_seg<1, 31, true >(sx, sy, sz, wtab, wave,           lane, xi, yi, zi, accA, racc);
    do_seg<0, 63, false>(sx, sy, sz, wtab, (wave + 1) & 7, lane, xi, yi, zi, accA, racc);
    do_seg<0, 63, false>(sx, sy, sz, wtab, (wave + 2) & 7, lane, xi, yi, zi, accA, racc);
    do_seg<0, 63, false>(sx, sy, sz, wtab, (wave + 3) & 7, lane, xi, yi, zi, accA, racc);
    if (wave < 4) do_seg<0, 31, false>(sx, sy, sz, wtab, wave + 4, lane, xi, yi, zi, accA, racc);
    else          do_seg<1, 32, false>(sx, sy, sz, wtab, wave - 4, lane, xi, yi, zi, accA, racc);

    __syncthreads();
    float s = accA + racc[tid];

    // Global-max division skipped: uniform positive scale cancels under the
    // final normalization (verified R0-R6).
    float ax = s * xi, ay = s * yi, az = s * zi;

    for (int off = 32; off > 0; off >>= 1) {
        ax += __shfl_down(ax, off, 64);
        ay += __shfl_down(ay, off, 64);
        az += __shfl_down(az, off, 64);
    }
    if (lane == 0) { rx[wave] = ax; ry[wave] = ay; rz[wave] = az; }
    __syncthreads();

    if (tid == 0) {
        float nx = 0.f, ny = 0.f, nz = 0.f;
        #pragma unroll
        for (int w = 0; w < 8; ++w) { nx += rx[w]; ny += ry[w]; nz += rz[w]; }
        float len2 = fmaf(nx, nx, fmaf(ny, ny, nz * nz));
        float inv  = rsqrtf(fmaxf(len2, 1e-20f));
        out[b * 3 + 0] = nx * inv;
        out[b * 3 + 1] = ny * inv;
        out[b * 3 + 2] = nz * inv;
    }
}

extern "C" void kernel_launch(void* const* d_in, const int* in_sizes, int n_in,
                              void* d_out, int out_size, void* d_ws, size_t ws_size,
                              hipStream_t stream) {
    const float* normals = (const float*)d_in[0];
    // d_in[1] (weights) is mathematically unused by the reference.
    float* out = (float*)d_out;
    normals_fused_kernel<<<BATCH, NPTS, 0, stream>>>(normals, out);
}

// Round 8
// 86.140 us; speedup vs baseline: 4.6622x; 1.0189x over previous
//
#include <hip/hip_runtime.h>
#include <math.h>

#define BATCH 512
#define NPTS  512

// Rotate a float ACROSS the full wave64 so that dst[l] = src[(l+1) & 63].
// DPP ctrl 0x134 = wave_rol:1 (verified R6, absmax 0.0).
__device__ __forceinline__ float rot1(float v) {
    return __int_as_float(__builtin_amdgcn_update_dpp(
        __float_as_int(v), __float_as_int(v), 0x134, 0xF, 0xF, false));
}

// EXACT path (used only to build the LUT): w(d) = exp2(-acos(d)*log2e),
// A&S 4.4.46 deg-7 poly pre-scaled by log2(e). Verified absmax 0.0 (R2-R6).
__device__ __forceinline__ float pair_w_exact(float d) {
    d = __builtin_amdgcn_fmed3f(d, -1.f, 1.f);
    float a  = fabsf(d);
    float t  = 1.f - a;
    float sq = __builtin_amdgcn_sqrtf(t);
    float p  = fmaf(-0.00182139f, a, 0.00962291f);
    p = fmaf(p, a, -0.02465296f);
    p = fmaf(p, a,  0.04456757f);
    p = fmaf(p, a, -0.07238623f);
    p = fmaf(p, a,  0.12836958f);
    p = fmaf(p, a, -0.30960063f);
    p = fmaf(p, a,  2.26618007f);
    float q = sq * p;
    float e = (d < 0.f) ? (4.53236014f - q) : q;
    return __builtin_amdgcn_exp2f(-e);
}

// LUT path (R7-verified, absmax 0.0039): 513 cells; cell 512 = {1,0} so the
// d==1 edge needs no min().
__device__ __forceinline__ float pair_w(float d, const float2* __restrict__ wtab) {
    float idx_f = __builtin_amdgcn_fmed3f(fmaf(d, 256.f, 256.f), 0.f, 512.f);
    int   idx   = (int)idx_f;
    float frac  = idx_f - (float)idx;
    float2 c = wtab[idx];                  // ds_read_b64
    return fmaf(frac, c.y, c.x);
}

// Segment vs B-chunk v, steps k=K0..K1 (pair: lane l vs B_{(l+k)&63}).
// B chunk + traveling transpose accumulator rotate in registers (R6-verified).
template<int K0, int K1, bool TAIL>
__device__ __forceinline__ void do_seg(
    const float* __restrict__ sx, const float* __restrict__ sy,
    const float* __restrict__ sz, const float2* __restrict__ wtab,
    int v, int lane, float xi, float yi, float zi,
    float& accA, float* __restrict__ racc)
{
    const int bi = v * 64 + lane;
    float bx = sx[bi], by = sy[bi], bz = sz[bi];
    float bacc = 0.f;
    #pragma unroll
    for (int r = 0; r < K0; ++r) { bx = rot1(bx); by = rot1(by); bz = rot1(bz); }
    #pragma unroll 8
    for (int k = K0; k <= K1; ++k) {
        float d = fmaf(xi, bx, fmaf(yi, by, zi * bz));
        float w = pair_w(d, wtab);
        accA += w;            // row i
        bacc += w;            // row (i+k) — traveling register
        bx = rot1(bx); by = rot1(by); bz = rot1(bz); bacc = rot1(bacc);
    }
    if (TAIL) {               // alignment K1+1, own-row only (self-chunk k=32)
        float d = fmaf(xi, bx, fmaf(yi, by, zi * bz));
        accA += pair_w(d, wtab);
    }
    const int m = (lane + K1 + 1) & 63;  // home slot of bacc after rotations
    atomicAdd(&racc[v * 64 + m], bacc);
}

// Each batch is split across TWO blocks (128 steps/thread each) so the grid
// is 1024 blocks = 4 blocks/CU = 8 waves/SIMD (R7 was latency-bound at 4).
// Row-sum linearity: partial weighted sums just add, merged in norm_kernel.
__global__ __launch_bounds__(512, 8) void pairs_kernel(
    const float* __restrict__ normals, float* __restrict__ ws)
{
    __shared__ float  sx[NPTS], sy[NPTS], sz[NPTS];
    __shared__ float  racc[NPTS];
    __shared__ float2 wtab[513];
    __shared__ float  rx[8], ry[8], rz[8];
    const int bx_id = blockIdx.x;
    const int b     = bx_id >> 1, half = bx_id & 1;
    const int tid   = threadIdx.x;
    const int wave  = tid >> 6, lane = tid & 63;
    const float* base = normals + (size_t)b * NPTS * 3;

    {   // build w(d) table (exact poly path)
        float d0 = (float)tid * (1.f / 256.f) - 1.f;
        float w0 = pair_w_exact(d0);
        float w1 = pair_w_exact(d0 + (1.f / 256.f));
        wtab[tid] = make_float2(w0, w1 - w0);
        if (tid == 0) wtab[512] = make_float2(1.f, 0.f);
    }
    for (int k = tid; k < NPTS * 3; k += NPTS) {
        float val = base[k];
        int r = k / 3, c = k - r * 3;
        float* dst = (c == 0) ? sx : (c == 1) ? sy : sz;
        dst[r] = val;
    }
    racc[tid] = 0.f;
    __syncthreads();

    const float xi = sx[tid], yi = sy[tid], zi = sz[tid];
    float accA = 0.f;

    // R6-verified schedule split into two balanced 128-step halves.
    if (half == 0) {
        do_seg<1, 31, true >(sx, sy, sz, wtab, wave,           lane, xi, yi, zi, accA, racc);
        do_seg<0, 63, false>(sx, sy, sz, wtab, (wave + 1) & 7, lane, xi, yi, zi, accA, racc);
        if (wave < 4) do_seg<0, 31, false>(sx, sy, sz, wtab, wave + 4, lane, xi, yi, zi, accA, racc);
        else          do_seg<1, 32, false>(sx, sy, sz, wtab, wave - 4, lane, xi, yi, zi, accA, racc);
    } else {
        do_seg<0, 63, false>(sx, sy, sz, wtab, (wave + 2) & 7, lane, xi, yi, zi, accA, racc);
        do_seg<0, 63, false>(sx, sy, sz, wtab, (wave + 3) & 7, lane, xi, yi, zi, accA, racc);
    }

    __syncthreads();
    float s = accA + racc[tid];   // partial row sum (this block's pairs only)

    // Global-max division skipped: uniform positive scale cancels under the
    // final normalization (verified R0-R7).
    float ax = s * xi, ay = s * yi, az = s * zi;

    for (int off = 32; off > 0; off >>= 1) {
        ax += __shfl_down(ax, off, 64);
        ay += __shfl_down(ay, off, 64);
        az += __shfl_down(az, off, 64);
    }
    if (lane == 0) { rx[wave] = ax; ry[wave] = ay; rz[wave] = az; }
    __syncthreads();

    if (tid == 0) {
        float nx = 0.f, ny = 0.f, nz = 0.f;
        #pragma unroll
        for (int w = 0; w < 8; ++w) { nx += rx[w]; ny += ry[w]; nz += rz[w]; }
        ((float4*)ws)[bx_id] = make_float4(nx, ny, nz, 0.f);  // no atomics
    }
}

__global__ __launch_bounds__(512) void norm_kernel(
    const float* __restrict__ ws, float* __restrict__ out)
{
    const int t = threadIdx.x;    // one thread per batch
    float4 p0 = ((const float4*)ws)[2 * t];
    float4 p1 = ((const float4*)ws)[2 * t + 1];
    float nx = p0.x + p1.x, ny = p0.y + p1.y, nz = p0.z + p1.z;
    float len2 = fmaf(nx, nx, fmaf(ny, ny, nz * nz));
    float inv  = rsqrtf(fmaxf(len2, 1e-20f));
    out[t * 3 + 0] = nx * inv;
    out[t * 3 + 1] = ny * inv;
    out[t * 3 + 2] = nz * inv;
}

extern "C" void kernel_launch(void* const* d_in, const int* in_sizes, int n_in,
                              void* d_out, int out_size, void* d_ws, size_t ws_size,
                              hipStream_t stream) {
    const float* normals = (const float*)d_in[0];
    // d_in[1] (weights) is mathematically unused by the reference.
    float* out = (float*)d_out;
    float* ws  = (float*)d_ws;
    pairs_kernel<<<2 * BATCH, NPTS, 0, stream>>>(normals, ws);
    norm_kernel<<<1, BATCH, 0, stream>>>(ws, out);
}

// Round 9
// 82.228 us; speedup vs baseline: 4.8841x; 1.0476x over previous
//
#include <hip/hip_runtime.h>
#include <math.h>

#define BATCH 512
#define NPTS  512

// Rotate a float ACROSS the full wave64 so that dst[l] = src[(l+1) & 63].
// DPP ctrl 0x134 = wave_rol:1 (verified R6/R7/R8, absmax <= 0.004).
__device__ __forceinline__ float rot1(float v) {
    return __int_as_float(__builtin_amdgcn_update_dpp(
        __float_as_int(v), __float_as_int(v), 0x134, 0xF, 0xF, false));
}

// EXACT path (used only to build the LUT): w(d) = exp2(-acos(d)*log2e),
// A&S 4.4.46 deg-7 poly pre-scaled by log2(e). Verified absmax 0.0 (R2-R6).
// Exact at endpoints: d=1 -> 1, d=-1 -> e^-pi.
__device__ __forceinline__ float pair_w_exact(float d) {
    d = __builtin_amdgcn_fmed3f(d, -1.f, 1.f);
    float a  = fabsf(d);
    float t  = 1.f - a;
    float sq = __builtin_amdgcn_sqrtf(t);
    float p  = fmaf(-0.00182139f, a, 0.00962291f);
    p = fmaf(p, a, -0.02465296f);
    p = fmaf(p, a,  0.04456757f);
    p = fmaf(p, a, -0.07238623f);
    p = fmaf(p, a,  0.12836958f);
    p = fmaf(p, a, -0.30960063f);
    p = fmaf(p, a,  2.26618007f);
    float q = sq * p;
    float e = (d < 0.f) ? (4.53236014f - q) : q;
    return __builtin_amdgcn_exp2f(-e);
}

// Nearest-neighbor LUT: 2049 f32 entries over [-1,1] (cell 1/1024).
// Index clamp doubles as the d-clamp (d>1 -> 2048 exact, d<-1 -> 0 exact).
// 4 VALU ops + one ds_read_b32 that feeds only the accumulate.
__device__ __forceinline__ float pair_w(float d, const float* __restrict__ wtab) {
    float idx_f = __builtin_amdgcn_fmed3f(fmaf(d, 1024.f, 1024.5f), 0.f, 2048.f);
    return wtab[(int)idx_f];
}

// Segment vs B-chunk v, steps k=K0..K1 (pair: lane l vs B_{(l+k)&63}).
// B chunk + traveling transpose accumulator rotate in registers (R6-verified).
template<int K0, int K1, bool TAIL>
__device__ __forceinline__ void do_seg(
    const float* __restrict__ sx, const float* __restrict__ sy,
    const float* __restrict__ sz, const float* __restrict__ wtab,
    int v, int lane, float xi, float yi, float zi,
    float& accA, float* __restrict__ racc)
{
    const int bi = v * 64 + lane;
    float bx = sx[bi], by = sy[bi], bz = sz[bi];
    float bacc = 0.f;
    #pragma unroll
    for (int r = 0; r < K0; ++r) { bx = rot1(bx); by = rot1(by); bz = rot1(bz); }
    #pragma unroll 16
    for (int k = K0; k <= K1; ++k) {
        float d = fmaf(xi, bx, fmaf(yi, by, zi * bz));
        float w = pair_w(d, wtab);
        accA += w;            // row i
        bacc += w;            // row (i+k) — traveling register
        bx = rot1(bx); by = rot1(by); bz = rot1(bz); bacc = rot1(bacc);
    }
    if (TAIL) {               // alignment K1+1, own-row only (self-chunk k=32)
        float d = fmaf(xi, bx, fmaf(yi, by, zi * bz));
        accA += pair_w(d, wtab);
    }
    const int m = (lane + K1 + 1) & 63;  // home slot of bacc after rotations
    atomicAdd(&racc[v * 64 + m], bacc);
}

// Two blocks per batch (R8): grid 1024 = 4 blocks/CU = 8 waves/SIMD.
__global__ __launch_bounds__(512, 8) void pairs_kernel(
    const float* __restrict__ normals, float* __restrict__ ws)
{
    __shared__ float sx[NPTS], sy[NPTS], sz[NPTS];
    __shared__ float racc[NPTS];
    __shared__ float wtab[2049];
    __shared__ float rx[8], ry[8], rz[8];
    const int bx_id = blockIdx.x;
    const int b     = bx_id >> 1, half = bx_id & 1;
    const int tid   = threadIdx.x;
    const int wave  = tid >> 6, lane = tid & 63;
    const float* base = normals + (size_t)b * NPTS * 3;

    // Build the w(d) table (one-time; exact poly path).
    for (int e = tid; e < 2049; e += NPTS)
        wtab[e] = pair_w_exact((float)e * (1.f / 1024.f) - 1.f);
    for (int k = tid; k < NPTS * 3; k += NPTS) {
        float val = base[k];
        int r = k / 3, c = k - r * 3;
        float* dst = (c == 0) ? sx : (c == 1) ? sy : sz;
        dst[r] = val;
    }
    racc[tid] = 0.f;
    __syncthreads();

    const float xi = sx[tid], yi = sy[tid], zi = sz[tid];
    float accA = 0.f;

    // R6-verified schedule split into two balanced 128-step halves.
    if (half == 0) {
        do_seg<1, 31, true >(sx, sy, sz, wtab, wave,           lane, xi, yi, zi, accA, racc);
        do_seg<0, 63, false>(sx, sy, sz, wtab, (wave + 1) & 7, lane, xi, yi, zi, accA, racc);
        if (wave < 4) do_seg<0, 31, false>(sx, sy, sz, wtab, wave + 4, lane, xi, yi, zi, accA, racc);
        else          do_seg<1, 32, false>(sx, sy, sz, wtab, wave - 4, lane, xi, yi, zi, accA, racc);
    } else {
        do_seg<0, 63, false>(sx, sy, sz, wtab, (wave + 2) & 7, lane, xi, yi, zi, accA, racc);
        do_seg<0, 63, false>(sx, sy, sz, wtab, (wave + 3) & 7, lane, xi, yi, zi, accA, racc);
    }

    __syncthreads();
    float s = accA + racc[tid];   // partial row sum (this block's pairs only)

    // Global-max division skipped: uniform positive scale cancels under the
    // final normalization (verified R0-R8).
    float ax = s * xi, ay = s * yi, az = s * zi;

    for (int off = 32; off > 0; off >>= 1) {
        ax += __shfl_down(ax, off, 64);
        ay += __shfl_down(ay, off, 64);
        az += __shfl_down(az, off, 64);
    }
    if (lane == 0) { rx[wave] = ax; ry[wave] = ay; rz[wave] = az; }
    __syncthreads();

    if (tid == 0) {
        float nx = 0.f, ny = 0.f, nz = 0.f;
        #pragma unroll
        for (int w = 0; w < 8; ++w) { nx += rx[w]; ny += ry[w]; nz += rz[w]; }
        ((float4*)ws)[bx_id] = make_float4(nx, ny, nz, 0.f);  // no atomics
    }
}

__global__ __launch_bounds__(512) void norm_kernel(
    const float* __restrict__ ws, float* __restrict__ out)
{
    const int t = threadIdx.x;    // one thread per batch
    float4 p0 = ((const float4*)ws)[2 * t];
    float4 p1 = ((const float4*)ws)[2 * t + 1];
    float nx = p0.x + p1.x, ny = p0.y + p1.y, nz = p0.z + p1.z;
    float len2 = fmaf(nx, nx, fmaf(ny, ny, nz * nz));
    float inv  = rsqrtf(fmaxf(len2, 1e-20f));
    out[t * 3 + 0] = nx * inv;
    out[t * 3 + 1] = ny * inv;
    out[t * 3 + 2] = nz * inv;
}

extern "C" void kernel_launch(void* const* d_in, const int* in_sizes, int n_in,
                              void* d_out, int out_size, void* d_ws, size_t ws_size,
                              hipStream_t stream) {
    const float* normals = (const float*)d_in[0];
    // d_in[1] (weights) is mathematically unused by the reference.
    float* out = (float*)d_out;
    float* ws  = (float*)d_ws;
    pairs_kernel<<<2 * BATCH, NPTS, 0, stream>>>(normals, ws);
    norm_kernel<<<1, BATCH, 0, stream>>>(ws, out);
}